// Round 13
// baseline (512.186 us; speedup 1.0000x reference)
//
#include <hip/hip_runtime.h>
#include <hip/hip_bf16.h>
#include <stdint.h>

typedef __hip_bfloat16 bf16;
typedef __attribute__((ext_vector_type(8))) short bf16x8;   // 8 bf16 = 4 VGPRs
typedef __attribute__((ext_vector_type(4))) float f32x4;
typedef __attribute__((ext_vector_type(16))) float f32x16;
typedef __attribute__((ext_vector_type(4))) unsigned short u16x4;

#define DEVI __device__ __forceinline__

static constexpr float LOG2E = 1.44269504088896f;
static constexpr float FACTOR_L2E = 0.0625f * 1.44269504088896f;  // (0.5/sqrt(64)) * log2(e)

DEVI unsigned short bfbits(float x) {
  return __builtin_bit_cast(unsigned short, __float2bfloat16(x));
}
DEVI float b2f(unsigned short u) {
  return __builtin_bit_cast(float, (uint32_t)u << 16);
}

// ---------------------------------------------------------------- converts
__global__ void cvt_plain(const float* __restrict__ src, bf16* __restrict__ dst, int n) {
  int i = (blockIdx.x * 256 + threadIdx.x) * 4;
  if (i >= n) return;
  float4 v = *reinterpret_cast<const float4*>(src + i);
  union { unsigned short u[4]; uint64_t d; } t;
  t.u[0] = bfbits(v.x); t.u[1] = bfbits(v.y); t.u[2] = bfbits(v.z); t.u[3] = bfbits(v.w);
  *reinterpret_cast<uint64_t*>(dst + i) = t.d;
}

// V [B,N,3,512] f32  ->  Vbf [3][B*N][512] bf16
__global__ void cvt_vperm(const float* __restrict__ src, bf16* __restrict__ dst) {
  int g = blockIdx.x * 256 + threadIdx.x;
  int k4  = (g & 127) * 4;
  int rem = g >> 7;                                // (b*2048+n)*3 + c
  int c  = rem % 3;
  int bn = rem / 3;
  float4 v = *reinterpret_cast<const float4*>(src + (size_t)rem * 512 + k4);
  union { unsigned short u[4]; uint64_t d; } t;
  t.u[0] = bfbits(v.x); t.u[1] = bfbits(v.y); t.u[2] = bfbits(v.z); t.u[3] = bfbits(v.w);
  *reinterpret_cast<uint64_t*>(dst + ((size_t)c * 8192 + bn) * 512 + k4) = t.d;
}

__global__ void cvt_weights(const float* __restrict__ wq, const float* __restrict__ wk,
                            const float* __restrict__ wv, const float* __restrict__ wvv,
                            const float* __restrict__ wo, const float* __restrict__ wvo,
                            bf16* __restrict__ dst) {
  int blk = blockIdx.x;
  const float* s; int off;
  if      (blk < 1024) { s = wq  + blk * 1024;          off = 0       + blk * 1024; }
  else if (blk < 2048) { s = wk  + (blk - 1024) * 1024; off = 1048576 + (blk - 1024) * 1024; }
  else if (blk < 2304) { s = wv  + (blk - 2048) * 1024; off = 2097152 + (blk - 2048) * 1024; }
  else if (blk < 2560) { s = wvv + (blk - 2304) * 1024; off = 2359296 + (blk - 2304) * 1024; }
  else if (blk < 2816) { s = wo  + (blk - 2560) * 1024; off = 2621440 + (blk - 2560) * 1024; }
  else                 { s = wvo + (blk - 2816) * 1024; off = 2883584 + (blk - 2816) * 1024; }
  int i = threadIdx.x * 4;
  float4 v = *reinterpret_cast<const float4*>(s + i);
  union { unsigned short u[4]; uint64_t d; } t;
  t.u[0] = bfbits(v.x); t.u[1] = bfbits(v.y); t.u[2] = bfbits(v.z); t.u[3] = bfbits(v.w);
  *reinterpret_cast<uint64_t*>(dst + off + i) = t.d;
}

// Bc[b][n][m] = mask ? (rbf + D) * log2(e) : -1e30   (bf16, into d_out)  [exp2-domain]
__global__ void bias_combine(const float* __restrict__ D, const float* __restrict__ rbf,
                             const int* __restrict__ mask, bf16* __restrict__ Bc) {
  size_t i = ((size_t)blockIdx.x * 256 + threadIdx.x) * 4;
  int col = (int)(i & 2047);
  int b   = (int)(i >> 22);
  float4 d = *reinterpret_cast<const float4*>(D + i);
  float4 r = *reinterpret_cast<const float4*>(rbf + i);
  const int* mrow = mask + b * 2048 + col;
  union { unsigned short u[4]; uint64_t dd; } t;
  t.u[0] = mrow[0] ? bfbits((d.x + r.x) * LOG2E) : bfbits(-1e30f);
  t.u[1] = mrow[1] ? bfbits((d.y + r.y) * LOG2E) : bfbits(-1e30f);
  t.u[2] = mrow[2] ? bfbits((d.z + r.z) * LOG2E) : bfbits(-1e30f);
  t.u[3] = mrow[3] ? bfbits((d.w + r.w) * LOG2E) : bfbits(-1e30f);
  *reinterpret_cast<uint64_t*>(Bc + i) = t.dd;
}

// ---------------------------------------------------------------- merged GEMMs  C = A @ W^T (+bias)
// (unchanged — verified)
template<int MODE>
__global__ __launch_bounds__(256, 2) void gemm2(const bf16* __restrict__ A,
                                                const bf16* __restrict__ W,
                                                const bf16* __restrict__ W2,
                                                const float* __restrict__ bias,
                                                const float* __restrict__ bias2,
                                                void* __restrict__ outp) {
  constexpr int K = 512;
  __shared__ bf16 As[2][4096];   // [128][32] linear 64B rows, chunk-XOR'd
  __shared__ bf16 Bs[2][4096];
  const int tid = threadIdx.x;
  const int wid = tid >> 6, lane = tid & 63;
  const int lr = lane & 15, lg = lane >> 4;
  const int wr = wid >> 1, wc = wid & 1;
  const int bm = blockIdx.y * 128, bn = blockIdx.x * 128;

  const bf16* Wp;
  if constexpr (MODE == 0) Wp = W;
  else Wp = (blockIdx.y < 64) ? W : W2;

  const int q  = tid >> 2;
  const int ch = ((tid & 3) ^ ((tid >> 3) & 3)) * 8;
  const bf16* Asrc0 = A  + (size_t)(bm + q) * K + ch;
  const bf16* Asrc1 = A  + (size_t)(bm + 64 + q) * K + ch;
  const bf16* Wsrc0 = Wp + (size_t)(bn + q) * K + ch;
  const bf16* Wsrc1 = Wp + (size_t)(bn + 64 + q) * K + ch;
  const int wofs = wid * 1024;

  f32x4 acc[4][4];
#pragma unroll
  for (int m = 0; m < 4; m++)
#pragma unroll
    for (int n = 0; n < 4; n++) acc[m][n] = (f32x4){0.f, 0.f, 0.f, 0.f};

  __builtin_amdgcn_global_load_lds((const char*)Asrc0, (char*)&As[0][0] + wofs,        16, 0, 0);
  __builtin_amdgcn_global_load_lds((const char*)Asrc1, (char*)&As[0][0] + 4096 + wofs, 16, 0, 0);
  __builtin_amdgcn_global_load_lds((const char*)Wsrc0, (char*)&Bs[0][0] + wofs,        16, 0, 0);
  __builtin_amdgcn_global_load_lds((const char*)Wsrc1, (char*)&Bs[0][0] + 4096 + wofs, 16, 0, 0);
  __syncthreads();

  const int fxor = ((lr >> 1) & 3) << 4;
  for (int kt = 0; kt < 16; ++kt) {
    const int cur = kt & 1;
    if (kt < 15) {
      const int nxt = cur ^ 1;
      __builtin_amdgcn_global_load_lds((const char*)(Asrc0 + (kt + 1) * 32), (char*)&As[nxt][0] + wofs,        16, 0, 0);
      __builtin_amdgcn_global_load_lds((const char*)(Asrc1 + (kt + 1) * 32), (char*)&As[nxt][0] + 4096 + wofs, 16, 0, 0);
      __builtin_amdgcn_global_load_lds((const char*)(Wsrc0 + (kt + 1) * 32), (char*)&Bs[nxt][0] + wofs,        16, 0, 0);
      __builtin_amdgcn_global_load_lds((const char*)(Wsrc1 + (kt + 1) * 32), (char*)&Bs[nxt][0] + 4096 + wofs, 16, 0, 0);
    }
    const char* AsC = (const char*)&As[cur][0];
    const char* BsC = (const char*)&Bs[cur][0];
    bf16x8 af[4], bfr[4];
#pragma unroll
    for (int m = 0; m < 4; m++) {
      const int row = wr * 64 + m * 16 + lr;
      af[m] = *reinterpret_cast<const bf16x8*>(AsC + row * 64 + ((lg << 4) ^ fxor));
    }
#pragma unroll
    for (int n = 0; n < 4; n++) {
      const int row = wc * 64 + n * 16 + lr;
      bfr[n] = *reinterpret_cast<const bf16x8*>(BsC + row * 64 + ((lg << 4) ^ fxor));
    }
#pragma unroll
    for (int m = 0; m < 4; m++)
#pragma unroll
      for (int n = 0; n < 4; n++)
        acc[m][n] = __builtin_amdgcn_mfma_f32_16x16x32_bf16(af[m], bfr[n], acc[m][n], 0, 0, 0);
    __syncthreads();
  }

#pragma unroll
  for (int m = 0; m < 4; m++) {
#pragma unroll
    for (int n = 0; n < 4; n++) {
      const int col  = bn + wc * 64 + n * 16 + lr;
      const int row0 = bm + wr * 64 + m * 16 + lg * 4;
      if constexpr (MODE == 0) {
        const int isK = col >> 11;
        const int col2 = col & 2047;
        const float bb = isK ? bias2[col2] : bias[col2];
        const int hh = col2 >> 8, t = col2 & 255;
        bf16* out = (bf16*)outp + (size_t)isK * 16777216;
#pragma unroll
        for (int qq = 0; qq < 4; qq++) {
          const int row = row0 + qq;
          const int b = row >> 11, nn = row & 2047;
          float v = acc[m][n][qq] + bb;
          if (!isK) v *= FACTOR_L2E;
          out[(size_t)((b * 8 + hh) * 2048 + nn) * 256 + t] = __float2bfloat16(v);
        }
      } else if constexpr (MODE == 1) {
        bf16* out = (bf16*)outp;
        const int hh = col >> 6, t = col & 63;
        int dimrow, nn; float bb;
        if (row0 < 8192) {
          const int b = row0 >> 11; nn = row0 & 2047;
          dimrow = (b * 8 + hh) * 256 + t;
          bb = bias[col];
        } else {
          const int r = row0 - 8192;
          const int c = r >> 13, b = (r >> 11) & 3; nn = r & 2047;
          dimrow = (b * 8 + hh) * 256 + 64 + c * 64 + t;
          bb = 0.f;
        }
        const int i4 = (nn >> 2) & 7;
        const int o4 = (i4 & 4) | ((i4 & 1) << 1) | ((i4 >> 1) & 1);
        const int nn2 = (nn & ~31) | (o4 << 2);
        union { unsigned short u[4]; uint64_t d; } pk;
#pragma unroll
        for (int qq = 0; qq < 4; qq++) pk.u[qq] = bfbits(acc[m][n][qq] + bb);
        *reinterpret_cast<uint64_t*>(out + (size_t)dimrow * 2048 + nn2) = pk.d;
      } else {
        float* out = (float*)outp;
        if (row0 < 8192) {
          const float bb = bias[col];
#pragma unroll
          for (int qq = 0; qq < 4; qq++)
            out[(size_t)(row0 + qq) * 512 + col] = acc[m][n][qq] + bb;
        } else {
#pragma unroll
          for (int qq = 0; qq < 4; qq++)
            out[4194304 + (size_t)(row0 - 8192 + qq) * 512 + col] = acc[m][n][qq];
        }
      }
    }
  }
}

// ---------------------------------------------------------------- flash attention
// grid 256, block 512 (8 waves x 32 q-rows), 1 block/CU. 4-buffer K/V ring (128KB LDS).
// T15 software pipeline: iteration t runs QK(t) [MFMA] || softmax(t-1) [VALU] || PV(t-1)
// [MFMA] in ONE barrier region; raw scores carried in regs (s_cur). stage(t+2) issued per
// iter; vmcnt(4) keeps it in flight while draining stage(t+1) -> tile t+1 ready next iter.
// stage(t+2) never collides with PV(t-1): (t+2) mod 4 != (t-1) mod 4.
__global__ __launch_bounds__(512, 1) void attn_kernel(
    const bf16* __restrict__ Qg, const bf16* __restrict__ Kg, const bf16* __restrict__ Vtg,
    const bf16* __restrict__ Bc, bf16* __restrict__ Hres, bf16* __restrict__ Vres) {
  __shared__ bf16 Ks[4][32 * 256];   // [key][dim] 512B rows, 16B-chunk ^= (key&31)
  __shared__ bf16 Vs[4][256 * 32];   // [dim][key] 64B rows, chunk ^= gg(row); perm'd key cols

  const int g = blockIdx.x;
  const int x = g & 7, loc = g >> 3;            // loc 0..31
  const int bh = x * 4 + (loc & 3);
  const int qt = loc >> 2;                       // 0..7
  const int b = bh >> 3, h = bh & 7;
  const int tid = threadIdx.x, w = tid >> 6, lane = tid & 63;
  const int lq = lane & 31, hi = lane >> 5;
  const int q0 = qt * 256 + w * 32;

  const bf16* Qb = Qg + (size_t)bh * 2048 * 256;
  const char* KbC = (const char*)(Kg + (size_t)bh * 2048 * 256);
  const char* VbC = (const char*)(Vtg + (size_t)bh * 256 * 2048);
  const bf16* Bb = Bc + ((size_t)(b * 2048 + q0 + lq)) * 2048 + hi * 4;

  // Q fragments: B-operand of mfma(K,Q): lane -> col q = lq, k-positions hi*8..+7
  bf16x8 qf[16];
#pragma unroll
  for (int kc = 0; kc < 16; kc++)
    qf[kc] = *reinterpret_cast<const bf16x8*>(Qb + (size_t)(q0 + lq) * 256 + kc * 16 + hi * 8);

  f32x16 O[8];
#pragma unroll
  for (int dt = 0; dt < 8; dt++)
#pragma unroll
    for (int r = 0; r < 16; r++) O[dt][r] = 0.f;
  float mrun = -INFINITY, lrun = 0.f;   // per-lane state for q-row q0 + lq (log2 domain)

  // ---- staging addresses (2 gload_lds each for K and V per wave; 8 waves per 16KB) ----
  const char* ksrc[2]; const char* vsrc[2];
#pragma unroll
  for (int i = 0; i < 2; i++) {
    const int X = w * 2048 + i * 1024 + lane * 16;
    const int krow = X >> 9, kcol = X & 511;
    ksrc[i] = KbC + (size_t)krow * 512 + (kcol ^ ((krow & 31) << 4));
    const int vrow = X >> 6;
    const int gg = ((vrow >> 1) ^ (vrow >> 3)) & 3;
    vsrc[i] = VbC + (size_t)vrow * 4096 + (((lane & 3) ^ gg) << 4);
  }
  char* ldsK = (char*)Ks + w * 2048;   // + buf*16384
  char* ldsV = (char*)Vs + w * 2048;

  const int kxor = lq << 4;

  // prologue: stage tiles 0 -> buf0, 1 -> buf1
#pragma unroll
  for (int i = 0; i < 2; i++) {
    __builtin_amdgcn_global_load_lds(ksrc[i], ldsK + i * 1024, 16, 0, 0);
    __builtin_amdgcn_global_load_lds(vsrc[i], ldsV + i * 1024, 16, 0, 0);
  }
  __builtin_amdgcn_sched_barrier(0);
#pragma unroll
  for (int i = 0; i < 2; i++) {
    __builtin_amdgcn_global_load_lds(ksrc[i] + 16384, ldsK + 16384 + i * 1024, 16, 0, 0);
    __builtin_amdgcn_global_load_lds(vsrc[i] + 64,    ldsV + 16384 + i * 1024, 16, 0, 0);
  }
  __builtin_amdgcn_sched_barrier(0);
  asm volatile("s_waitcnt vmcnt(4)" ::: "memory");   // tile0 landed; stage(1) in flight
  __builtin_amdgcn_sched_barrier(0);
  __builtin_amdgcn_s_barrier();

  // peel t=0: QK(0) + bias(0) + stage(2); no softmax/PV yet
  f32x16 s_cur;
#pragma unroll
  for (int r = 0; r < 16; r++) s_cur[r] = 0.f;
#pragma unroll
  for (int kc = 0; kc < 16; kc++) {
    bf16x8 kf = *reinterpret_cast<const bf16x8*>((const char*)Ks + lq * 512 + ((kc * 32 + hi * 16) ^ kxor));
    s_cur = __builtin_amdgcn_mfma_f32_32x32x16_bf16(kf, qf[kc], s_cur, 0, 0, 0);
  }
  u16x4 bgA[4];
#pragma unroll
  for (int i = 0; i < 4; i++) bgA[i] = *reinterpret_cast<const u16x4*>(Bb + i * 8);
  __builtin_amdgcn_sched_barrier(0);
#pragma unroll
  for (int i = 0; i < 2; i++) {
    __builtin_amdgcn_global_load_lds(ksrc[i] + 2 * 16384, ldsK + 2 * 16384 + i * 1024, 16, 0, 0);
    __builtin_amdgcn_global_load_lds(vsrc[i] + 2 * 64,    ldsV + 2 * 16384 + i * 1024, 16, 0, 0);
  }
  __builtin_amdgcn_sched_barrier(0);
  asm volatile("s_waitcnt vmcnt(4)" ::: "memory");   // drain stage(1); keep stage(2)
  __builtin_amdgcn_sched_barrier(0);
  __builtin_amdgcn_s_barrier();

  int cq = 1, cp = 0, cs = 3;   // at iter t: cq=t%4, cp=(t-1)%4, cs=(t+2)%4

#pragma unroll 1
  for (int t = 1; t < 64; ++t) {
    // bias(t) prefetch (used by softmax(t) next iteration)
    u16x4 bgB[4];
#pragma unroll
    for (int i = 0; i < 4; i++)
      bgB[i] = *reinterpret_cast<const u16x4*>(Bb + (size_t)t * 32 + i * 8);
    __builtin_amdgcn_sched_barrier(0);
    // stage(t+2) into ring buffer cs (tail: dead re-stage of tile 63)
    {
      const int tn = (t < 62) ? t + 2 : 63;
#pragma unroll
      for (int i = 0; i < 2; i++) {
        __builtin_amdgcn_global_load_lds(ksrc[i] + (size_t)tn * 16384, ldsK + cs * 16384 + i * 1024, 16, 0, 0);
        __builtin_amdgcn_global_load_lds(vsrc[i] + (size_t)tn * 64,    ldsV + cs * 16384 + i * 1024, 16, 0, 0);
      }
    }
    __builtin_amdgcn_sched_barrier(0);

    // ---- QK(t) on buf cq (independent of softmax/PV below -> interleaves) ----
    f32x16 sn;
#pragma unroll
    for (int r = 0; r < 16; r++) sn[r] = 0.f;
    const char* KsC = (const char*)Ks + cq * 16384;
#pragma unroll
    for (int kc = 0; kc < 16; kc++) {
      bf16x8 kf = *reinterpret_cast<const bf16x8*>(KsC + lq * 512 + ((kc * 32 + hi * 16) ^ kxor));
      sn = __builtin_amdgcn_mfma_f32_32x32x16_bf16(kf, qf[kc], sn, 0, 0, 0);
    }

    // ---- softmax(t-1): s_cur + bgA ----
    float sc[16];
#pragma unroll
    for (int r = 0; r < 16; r++)
      sc[r] = s_cur[r] + b2f((unsigned short)bgA[r >> 2][r & 3]);
    float m0 = fmaxf(sc[0], sc[1]),  m1 = fmaxf(sc[2], sc[3]);
    float m2 = fmaxf(sc[4], sc[5]),  m3 = fmaxf(sc[6], sc[7]);
    float m4 = fmaxf(sc[8], sc[9]),  m5 = fmaxf(sc[10], sc[11]);
    float m6 = fmaxf(sc[12], sc[13]), m7 = fmaxf(sc[14], sc[15]);
    float pmax = fmaxf(fmaxf(fmaxf(m0, m1), fmaxf(m2, m3)),
                       fmaxf(fmaxf(m4, m5), fmaxf(m6, m7)));
    pmax = fmaxf(pmax, __shfl_xor(pmax, 32));
    const bool ok = (pmax <= mrun + 8.f);
    if (!__all((int)ok)) {
      const float mnew = fmaxf(mrun, pmax);
      const float scq = exp2f(mrun - mnew);
      mrun = mnew;
      lrun *= scq;
      float sfac[16];
#pragma unroll
      for (int r = 0; r < 16; r++) sfac[r] = __shfl(scq, (r & 3) + 8 * (r >> 2) + 4 * hi);
#pragma unroll
      for (int dt = 0; dt < 8; dt++)
#pragma unroll
        for (int r = 0; r < 16; r++) O[dt][r] *= sfac[r];
    }
    union { unsigned short u[8]; bf16x8 v; } pa0, pa1;
    float rs = 0.f;
#pragma unroll
    for (int j = 0; j < 8; j++) {
      const float p = exp2f(sc[j] - mrun);
      pa0.u[j] = bfbits(p);
      rs += b2f(pa0.u[j]);
    }
#pragma unroll
    for (int j = 0; j < 8; j++) {
      const float p = exp2f(sc[8 + j] - mrun);
      pa1.u[j] = bfbits(p);
      rs += b2f(pa1.u[j]);
    }
    rs += __shfl_xor(rs, 32);
    lrun += rs;

    // ---- PV(t-1) on buf cp ----
    const char* VsC = (const char*)Vs + cp * 16384;
#pragma unroll
    for (int dt = 0; dt < 8; dt++) {
      const int row = dt * 32 + lq;
      const int gg = ((row >> 1) ^ (row >> 3)) & 3;
      bf16x8 v0 = *reinterpret_cast<const bf16x8*>(VsC + row * 64 + ((hi ^ gg) << 4));
      bf16x8 v1 = *reinterpret_cast<const bf16x8*>(VsC + row * 64 + (((2 + hi) ^ gg) << 4));
      O[dt] = __builtin_amdgcn_mfma_f32_32x32x16_bf16(pa0.v, v0, O[dt], 0, 0, 0);
      O[dt] = __builtin_amdgcn_mfma_f32_32x32x16_bf16(pa1.v, v1, O[dt], 0, 0, 0);
    }

    // drain stage(t+1) (keep stage(t+2)); bias(t) also drained -> tile t+1 + bgB ready
    asm volatile("s_waitcnt vmcnt(4)" ::: "memory");
    __builtin_amdgcn_sched_barrier(0);
    __builtin_amdgcn_s_barrier();

    s_cur = sn;
#pragma unroll
    for (int i = 0; i < 4; i++) bgA[i] = bgB[i];
    cq = (cq + 1) & 3; cp = (cp + 1) & 3; cs = (cs + 1) & 3;
  }

  // ---- epilogue: softmax(63) + PV(63) on buf cp (= 3; never overwritten by dead stages) ----
  {
    float sc[16];
#pragma unroll
    for (int r = 0; r < 16; r++)
      sc[r] = s_cur[r] + b2f((unsigned short)bgA[r >> 2][r & 3]);
    float m0 = fmaxf(sc[0], sc[1]),  m1 = fmaxf(sc[2], sc[3]);
    float m2 = fmaxf(sc[4], sc[5]),  m3 = fmaxf(sc[6], sc[7]);
    float m4 = fmaxf(sc[8], sc[9]),  m5 = fmaxf(sc[10], sc[11]);
    float m6 = fmaxf(sc[12], sc[13]), m7 = fmaxf(sc[14], sc[15]);
    float pmax = fmaxf(fmaxf(fmaxf(m0, m1), fmaxf(m2, m3)),
                       fmaxf(fmaxf(m4, m5), fmaxf(m6, m7)));
    pmax = fmaxf(pmax, __shfl_xor(pmax, 32));
    const bool ok = (pmax <= mrun + 8.f);
    if (!__all((int)ok)) {
      const float mnew = fmaxf(mrun, pmax);
      const float scq = exp2f(mrun - mnew);
      mrun = mnew;
      lrun *= scq;
      float sfac[16];
#pragma unroll
      for (int r = 0; r < 16; r++) sfac[r] = __shfl(scq, (r & 3) + 8 * (r >> 2) + 4 * hi);
#pragma unroll
      for (int dt = 0; dt < 8; dt++)
#pragma unroll
        for (int r = 0; r < 16; r++) O[dt][r] *= sfac[r];
    }
    union { unsigned short u[8]; bf16x8 v; } pa0, pa1;
    float rs = 0.f;
#pragma unroll
    for (int j = 0; j < 8; j++) {
      const float p = exp2f(sc[j] - mrun);
      pa0.u[j] = bfbits(p);
      rs += b2f(pa0.u[j]);
    }
#pragma unroll
    for (int j = 0; j < 8; j++) {
      const float p = exp2f(sc[8 + j] - mrun);
      pa1.u[j] = bfbits(p);
      rs += b2f(pa1.u[j]);
    }
    rs += __shfl_xor(rs, 32);
    lrun += rs;
    const char* VsC = (const char*)Vs + cp * 16384;
#pragma unroll
    for (int dt = 0; dt < 8; dt++) {
      const int row = dt * 32 + lq;
      const int gg = ((row >> 1) ^ (row >> 3)) & 3;
      bf16x8 v0 = *reinterpret_cast<const bf16x8*>(VsC + row * 64 + ((hi ^ gg) << 4));
      bf16x8 v1 = *reinterpret_cast<const bf16x8*>(VsC + row * 64 + (((2 + hi) ^ gg) << 4));
      O[dt] = __builtin_amdgcn_mfma_f32_32x32x16_bf16(pa0.v, v0, O[dt], 0, 0, 0);
      O[dt] = __builtin_amdgcn_mfma_f32_32x32x16_bf16(pa1.v, v1, O[dt], 0, 0, 0);
    }
  }

  // final normalize + store: O[dt] col = dim dt*32+lq, rows = q kr(r)
  const float rli = 1.0f / lrun;
  float rl[16];
#pragma unroll
  for (int r = 0; r < 16; r++) rl[r] = __shfl(rli, (r & 3) + 8 * (r >> 2) + 4 * hi);
#pragma unroll
  for (int dt = 0; dt < 8; dt++) {
    const int d = dt * 32 + lq;
#pragma unroll
    for (int r = 0; r < 16; r++) {
      const int row = q0 + (r & 3) + 8 * (r >> 2) + 4 * hi;
      const float v = O[dt][r] * rl[r];
      if (d < 64) {
        Hres[(size_t)(b * 2048 + row) * 512 + h * 64 + d] = __float2bfloat16(v);
      } else {
        const int c = (d - 64) >> 6, t = (d - 64) & 63;
        Vres[((size_t)(b * 2048 + row) * 3 + c) * 512 + h * 64 + t] = __float2bfloat16(v);
      }
    }
  }
}

// ---------------------------------------------------------------- launch
extern "C" void kernel_launch(void* const* d_in, const int* in_sizes, int n_in,
                              void* d_out, int out_size, void* d_ws, size_t ws_size,
                              hipStream_t stream) {
  const float* H   = (const float*)d_in[0];
  const float* V   = (const float*)d_in[1];
  const float* Dm  = (const float*)d_in[2];
  const float* rbf = (const float*)d_in[3];
  const int*   mask= (const int*)d_in[4];
  const float* Wq  = (const float*)d_in[5];
  const float* bq  = (const float*)d_in[6];
  const float* Wk  = (const float*)d_in[7];
  const float* bk  = (const float*)d_in[8];
  const float* Wv  = (const float*)d_in[9];
  const float* bv  = (const float*)d_in[10];
  const float* Wvv = (const float*)d_in[11];
  const float* Wo  = (const float*)d_in[12];
  const float* bo  = (const float*)d_in[13];
  const float* Wvo = (const float*)d_in[14];

  char* ws = (char*)d_ws;
  bf16* Hbf  = (bf16*)(ws);                    // Hbf||Vbf contiguous [32768,512]
  bf16* Wall = (bf16*)(ws + 33554432);
  bf16* Qw   = (bf16*)(ws + 39845888);         // Qw||Kw contiguous
  bf16* Kw   = Qw + 16777216;
  bf16* Vtw  = (bf16*)(ws + 106954752);
  bf16* Hres = Hbf;                             // aliases (attn output overwrites inputs' bf16)
  bf16* Wqb  = Wall;
  bf16* Wvb  = Wall + 2097152;
  bf16* Wvvb = Wall + 2359296;
  bf16* Wob  = Wall + 2621440;
  bf16* Wvob = Wall + 2883584;
  bf16* Bcb  = (bf16*)d_out;                   // 33.5MB bf16 in d_out; read fully by attn
                                               // before the final GEMM overwrites d_out

  bias_combine<<<16384, 256, 0, stream>>>(Dm, rbf, mask, Bcb);
  cvt_plain<<<4096, 256, 0, stream>>>(H, Hbf, 4194304);
  cvt_vperm<<<12288, 256, 0, stream>>>(V, Hbf + 4194304);
  cvt_weights<<<3072, 256, 0, stream>>>(Wq, Wk, Wv, Wvv, Wo, Wvo, Wall);

  // Q||K projection: A=Hbf, W=Wq||Wk (contiguous in Wall), out=Qw||Kw
  gemm2<0><<<dim3(32, 64), 256, 0, stream>>>(Hbf, Wqb, nullptr, bq, bk, Qw);
  // Hv||Vv -> Vt: A=Hbf||Vbf, W selected per block-row
  gemm2<1><<<dim3(4, 256), 256, 0, stream>>>(Hbf, Wvb, Wvvb, bv, nullptr, Vtw);

  attn_kernel<<<256, 512, 0, stream>>>(Qw, Kw, Vtw, Bcb, Hres, Hbf + 4194304);

  // output projection: A=Hres||Vres, W selected per block-row, out=d_out (f32)
  gemm2<2><<<dim3(4, 256), 256, 0, stream>>>(Hbf, Wob, Wvob, bo, nullptr, d_out);
}

// Round 14
// 436.190 us; speedup vs baseline: 1.1742x; 1.1742x over previous
//
#include <hip/hip_runtime.h>
#include <hip/hip_bf16.h>
#include <stdint.h>

typedef __hip_bfloat16 bf16;
typedef __attribute__((ext_vector_type(8))) short bf16x8;   // 8 bf16 = 4 VGPRs
typedef __attribute__((ext_vector_type(4))) float f32x4;
typedef __attribute__((ext_vector_type(16))) float f32x16;
typedef __attribute__((ext_vector_type(4))) unsigned short u16x4;

#define DEVI __device__ __forceinline__

static constexpr float FACTOR = 0.0625f;  // 0.5 / sqrt(64)

DEVI unsigned short bfbits(float x) {
  return __builtin_bit_cast(unsigned short, __float2bfloat16(x));
}
DEVI float b2f(unsigned short u) {
  return __builtin_bit_cast(float, (uint32_t)u << 16);
}

// ---------------------------------------------------------------- converts
__global__ void cvt_plain(const float* __restrict__ src, bf16* __restrict__ dst, int n) {
  int i = (blockIdx.x * 256 + threadIdx.x) * 4;
  if (i >= n) return;
  float4 v = *reinterpret_cast<const float4*>(src + i);
  union { unsigned short u[4]; uint64_t d; } t;
  t.u[0] = bfbits(v.x); t.u[1] = bfbits(v.y); t.u[2] = bfbits(v.z); t.u[3] = bfbits(v.w);
  *reinterpret_cast<uint64_t*>(dst + i) = t.d;
}

// V [B,N,3,512] f32  ->  Vbf [3][B*N][512] bf16
__global__ void cvt_vperm(const float* __restrict__ src, bf16* __restrict__ dst) {
  int g = blockIdx.x * 256 + threadIdx.x;
  int k4  = (g & 127) * 4;
  int rem = g >> 7;                                // (b*2048+n)*3 + c
  int c  = rem % 3;
  int bn = rem / 3;
  float4 v = *reinterpret_cast<const float4*>(src + (size_t)rem * 512 + k4);
  union { unsigned short u[4]; uint64_t d; } t;
  t.u[0] = bfbits(v.x); t.u[1] = bfbits(v.y); t.u[2] = bfbits(v.z); t.u[3] = bfbits(v.w);
  *reinterpret_cast<uint64_t*>(dst + ((size_t)c * 8192 + bn) * 512 + k4) = t.d;
}

__global__ void cvt_weights(const float* __restrict__ wq, const float* __restrict__ wk,
                            const float* __restrict__ wv, const float* __restrict__ wvv,
                            const float* __restrict__ wo, const float* __restrict__ wvo,
                            bf16* __restrict__ dst) {
  int blk = blockIdx.x;
  const float* s; int off;
  if      (blk < 1024) { s = wq  + blk * 1024;          off = 0       + blk * 1024; }
  else if (blk < 2048) { s = wk  + (blk - 1024) * 1024; off = 1048576 + (blk - 1024) * 1024; }
  else if (blk < 2304) { s = wv  + (blk - 2048) * 1024; off = 2097152 + (blk - 2048) * 1024; }
  else if (blk < 2560) { s = wvv + (blk - 2304) * 1024; off = 2359296 + (blk - 2304) * 1024; }
  else if (blk < 2816) { s = wo  + (blk - 2560) * 1024; off = 2621440 + (blk - 2560) * 1024; }
  else                 { s = wvo + (blk - 2816) * 1024; off = 2883584 + (blk - 2816) * 1024; }
  int i = threadIdx.x * 4;
  float4 v = *reinterpret_cast<const float4*>(s + i);
  union { unsigned short u[4]; uint64_t d; } t;
  t.u[0] = bfbits(v.x); t.u[1] = bfbits(v.y); t.u[2] = bfbits(v.z); t.u[3] = bfbits(v.w);
  *reinterpret_cast<uint64_t*>(dst + off + i) = t.d;
}

// Bc[b][n][m] = mask[b][m] ? rbf[b][n][m] + D[b][n][m] : -1e30   (bf16, into d_out)
__global__ void bias_combine(const float* __restrict__ D, const float* __restrict__ rbf,
                             const int* __restrict__ mask, bf16* __restrict__ Bc) {
  size_t i = ((size_t)blockIdx.x * 256 + threadIdx.x) * 4;
  int col = (int)(i & 2047);
  int b   = (int)(i >> 22);
  float4 d = *reinterpret_cast<const float4*>(D + i);
  float4 r = *reinterpret_cast<const float4*>(rbf + i);
  const int* mrow = mask + b * 2048 + col;
  union { unsigned short u[4]; uint64_t dd; } t;
  t.u[0] = mrow[0] ? bfbits(d.x + r.x) : bfbits(-1e30f);
  t.u[1] = mrow[1] ? bfbits(d.y + r.y) : bfbits(-1e30f);
  t.u[2] = mrow[2] ? bfbits(d.z + r.z) : bfbits(-1e30f);
  t.u[3] = mrow[3] ? bfbits(d.w + r.w) : bfbits(-1e30f);
  *reinterpret_cast<uint64_t*>(Bc + i) = t.dd;
}

// ---------------------------------------------------------------- merged GEMMs  C = A @ W^T (+bias)
// 128x128 tile, BK=32, 4 waves, double-buffered LDS via global_load_lds (linear dest,
// involutive chunk-XOR c ^= ((row>>1)&3) on source and fragment read).
// MODE 0 (grid 32x64):  A=Hbf[8192], W=Wall[4096] (Wq||Wk). col<2048 -> Q ((acc+bq)*FACTOR),
//                       else K (acc+bk). out Qw||Kw [bh][n][256].
// MODE 1 (grid 4x256):  A=Hbf||Vbf[32768], W = by<64 ? Wv : Wvv, bias bv for by<64.
//                       out Vt[(bh*256 + dim)*2048 + perm(n)]  (perm: o4=(i4&4)|((i4&1)<<1)|((i4>>1)&1))
// MODE 2 (grid 4x256):  A=Hres||Vres[32768], W = by<64 ? Wo : Wvo, bias bo for by<64.
//                       out f32 d_out (H part) / d_out+4194304 (V part).
template<int MODE>
__global__ __launch_bounds__(256, 2) void gemm2(const bf16* __restrict__ A,
                                                const bf16* __restrict__ W,
                                                const bf16* __restrict__ W2,
                                                const float* __restrict__ bias,
                                                const float* __restrict__ bias2,
                                                void* __restrict__ outp) {
  constexpr int K = 512;
  __shared__ bf16 As[2][4096];   // [128][32] linear 64B rows, chunk-XOR'd
  __shared__ bf16 Bs[2][4096];
  const int tid = threadIdx.x;
  const int wid = tid >> 6, lane = tid & 63;
  const int lr = lane & 15, lg = lane >> 4;
  const int wr = wid >> 1, wc = wid & 1;
  const int bm = blockIdx.y * 128, bn = blockIdx.x * 128;

  const bf16* Wp;
  if constexpr (MODE == 0) Wp = W;
  else Wp = (blockIdx.y < 64) ? W : W2;

  const int q  = tid >> 2;
  const int ch = ((tid & 3) ^ ((tid >> 3) & 3)) * 8;
  const bf16* Asrc0 = A  + (size_t)(bm + q) * K + ch;
  const bf16* Asrc1 = A  + (size_t)(bm + 64 + q) * K + ch;
  const bf16* Wsrc0 = Wp + (size_t)(bn + q) * K + ch;
  const bf16* Wsrc1 = Wp + (size_t)(bn + 64 + q) * K + ch;
  const int wofs = wid * 1024;

  f32x4 acc[4][4];
#pragma unroll
  for (int m = 0; m < 4; m++)
#pragma unroll
    for (int n = 0; n < 4; n++) acc[m][n] = (f32x4){0.f, 0.f, 0.f, 0.f};

  __builtin_amdgcn_global_load_lds((const char*)Asrc0, (char*)&As[0][0] + wofs,        16, 0, 0);
  __builtin_amdgcn_global_load_lds((const char*)Asrc1, (char*)&As[0][0] + 4096 + wofs, 16, 0, 0);
  __builtin_amdgcn_global_load_lds((const char*)Wsrc0, (char*)&Bs[0][0] + wofs,        16, 0, 0);
  __builtin_amdgcn_global_load_lds((const char*)Wsrc1, (char*)&Bs[0][0] + 4096 + wofs, 16, 0, 0);
  __syncthreads();

  const int fxor = ((lr >> 1) & 3) << 4;
  for (int kt = 0; kt < 16; ++kt) {
    const int cur = kt & 1;
    if (kt < 15) {
      const int nxt = cur ^ 1;
      __builtin_amdgcn_global_load_lds((const char*)(Asrc0 + (kt + 1) * 32), (char*)&As[nxt][0] + wofs,        16, 0, 0);
      __builtin_amdgcn_global_load_lds((const char*)(Asrc1 + (kt + 1) * 32), (char*)&As[nxt][0] + 4096 + wofs, 16, 0, 0);
      __builtin_amdgcn_global_load_lds((const char*)(Wsrc0 + (kt + 1) * 32), (char*)&Bs[nxt][0] + wofs,        16, 0, 0);
      __builtin_amdgcn_global_load_lds((const char*)(Wsrc1 + (kt + 1) * 32), (char*)&Bs[nxt][0] + 4096 + wofs, 16, 0, 0);
    }
    const char* AsC = (const char*)&As[cur][0];
    const char* BsC = (const char*)&Bs[cur][0];
    bf16x8 af[4], bfr[4];
#pragma unroll
    for (int m = 0; m < 4; m++) {
      const int row = wr * 64 + m * 16 + lr;
      af[m] = *reinterpret_cast<const bf16x8*>(AsC + row * 64 + ((lg << 4) ^ fxor));
    }
#pragma unroll
    for (int n = 0; n < 4; n++) {
      const int row = wc * 64 + n * 16 + lr;
      bfr[n] = *reinterpret_cast<const bf16x8*>(BsC + row * 64 + ((lg << 4) ^ fxor));
    }
#pragma unroll
    for (int m = 0; m < 4; m++)
#pragma unroll
      for (int n = 0; n < 4; n++)
        acc[m][n] = __builtin_amdgcn_mfma_f32_16x16x32_bf16(af[m], bfr[n], acc[m][n], 0, 0, 0);
    __syncthreads();
  }

#pragma unroll
  for (int m = 0; m < 4; m++) {
#pragma unroll
    for (int n = 0; n < 4; n++) {
      const int col  = bn + wc * 64 + n * 16 + lr;
      const int row0 = bm + wr * 64 + m * 16 + lg * 4;
      if constexpr (MODE == 0) {
        const int isK = col >> 11;
        const int col2 = col & 2047;
        const float bb = isK ? bias2[col2] : bias[col2];
        const int hh = col2 >> 8, t = col2 & 255;
        bf16* out = (bf16*)outp + (size_t)isK * 16777216;
#pragma unroll
        for (int qq = 0; qq < 4; qq++) {
          const int row = row0 + qq;
          const int b = row >> 11, nn = row & 2047;
          float v = acc[m][n][qq] + bb;
          if (!isK) v *= FACTOR;
          out[(size_t)((b * 8 + hh) * 2048 + nn) * 256 + t] = __float2bfloat16(v);
        }
      } else if constexpr (MODE == 1) {
        bf16* out = (bf16*)outp;
        const int hh = col >> 6, t = col & 63;
        int dimrow, nn; float bb;
        if (row0 < 8192) {
          const int b = row0 >> 11; nn = row0 & 2047;
          dimrow = (b * 8 + hh) * 256 + t;
          bb = bias[col];
        } else {
          const int r = row0 - 8192;
          const int c = r >> 13, b = (r >> 11) & 3; nn = r & 2047;
          dimrow = (b * 8 + hh) * 256 + 64 + c * 64 + t;
          bb = 0.f;
        }
        const int i4 = (nn >> 2) & 7;
        const int o4 = (i4 & 4) | ((i4 & 1) << 1) | ((i4 >> 1) & 1);
        const int nn2 = (nn & ~31) | (o4 << 2);
        union { unsigned short u[4]; uint64_t d; } pk;
#pragma unroll
        for (int qq = 0; qq < 4; qq++) pk.u[qq] = bfbits(acc[m][n][qq] + bb);
        *reinterpret_cast<uint64_t*>(out + (size_t)dimrow * 2048 + nn2) = pk.d;
      } else {
        float* out = (float*)outp;
        if (row0 < 8192) {
          const float bb = bias[col];
#pragma unroll
          for (int qq = 0; qq < 4; qq++)
            out[(size_t)(row0 + qq) * 512 + col] = acc[m][n][qq] + bb;
        } else {
#pragma unroll
          for (int qq = 0; qq < 4; qq++)
            out[4194304 + (size_t)(row0 - 8192 + qq) * 512 + col] = acc[m][n][qq];
        }
      }
    }
  }
}

// ---------------------------------------------------------------- flash attention
// grid 512, block 256 (4 waves x 32 q-rows = 128 q/block), 2 blocks/CU.
// 32x32x16 MFMA. Swapped QK^T: S^T = mfma(K, Q) -> lane holds q = lane&31, 16 keys at
// kr(r) = (r&3)+8*(r>>2)+4*hi. V keys stored pre-permuted to match -> P packs directly
// into the PV A-fragment (no cross-lane ops). Always-rescale online softmax.
// Round-6 body verbatim (281 us measured). No setprio, single QK chain, __expf.
__global__ __launch_bounds__(256, 2) void attn_kernel(
    const bf16* __restrict__ Qg, const bf16* __restrict__ Kg, const bf16* __restrict__ Vtg,
    const bf16* __restrict__ Bc, bf16* __restrict__ Hres, bf16* __restrict__ Vres) {
  __shared__ bf16 Ks[2][32 * 256];   // [key][dim] 512B rows, 16B-chunk ^= (key&31)
  __shared__ bf16 Vs[2][256 * 32];   // [dim][key] 64B rows, chunk ^= gg(row); perm'd key cols

  const int g = blockIdx.x;
  const int x = g & 7, loc = g >> 3;            // loc 0..63
  const int bh = x * 4 + (loc & 3);
  const int qt = loc >> 2;                       // 0..15
  const int b = bh >> 3, h = bh & 7;
  const int tid = threadIdx.x, w = tid >> 6, lane = tid & 63;
  const int lq = lane & 31, hi = lane >> 5;
  const int q0 = qt * 128 + w * 32;

  const bf16* Qb = Qg + (size_t)bh * 2048 * 256;
  const char* KbC = (const char*)(Kg + (size_t)bh * 2048 * 256);
  const char* VbC = (const char*)(Vtg + (size_t)bh * 256 * 2048);
  const bf16* Bb = Bc + ((size_t)(b * 2048 + q0 + lq)) * 2048 + hi * 4;

  // Q fragments: B-operand of mfma(K,Q): lane -> col q = lq, k-positions hi*8..+7
  bf16x8 qf[16];
#pragma unroll
  for (int kc = 0; kc < 16; kc++)
    qf[kc] = *reinterpret_cast<const bf16x8*>(Qb + (size_t)(q0 + lq) * 256 + kc * 16 + hi * 8);

  f32x16 O[8];
#pragma unroll
  for (int dt = 0; dt < 8; dt++)
#pragma unroll
    for (int r = 0; r < 16; r++) O[dt][r] = 0.f;
  float mrun = -INFINITY, lrun = 0.f;   // per-lane state for q-row q0 + lq

  // ---- staging addresses (4 gload_lds each for K and V per wave) ----
  const char* ksrc[4]; const char* vsrc[4];
#pragma unroll
  for (int i = 0; i < 4; i++) {
    const int krow = w * 8 + 2 * i + hi;
    ksrc[i] = KbC + (size_t)krow * 512 + ((lq * 16) ^ ((krow & 31) << 4));
    const int vrow = w * 64 + i * 16 + (lane >> 2);
    const int gg = ((vrow >> 1) ^ (vrow >> 3)) & 3;
    vsrc[i] = VbC + (size_t)vrow * 4096 + (((lane & 3) ^ gg) << 4);
  }

  // prologue: stage tile 0 into buf 0
  {
    char* dK = (char*)&Ks[0][0] + w * 4096;
    char* dV = (char*)&Vs[0][0] + w * 4096;
#pragma unroll
    for (int i = 0; i < 4; i++) {
      __builtin_amdgcn_global_load_lds(ksrc[i], dK + i * 1024, 16, 0, 0);
      __builtin_amdgcn_global_load_lds(vsrc[i], dV + i * 1024, 16, 0, 0);
    }
  }
  asm volatile("s_waitcnt vmcnt(0)" ::: "memory");
  __builtin_amdgcn_sched_barrier(0);
  __builtin_amdgcn_s_barrier();

  for (int kt = 0; kt < 64; ++kt) {
    const int cur = kt & 1;
    // bias for current tile: bg[i][j] = bias[q0+lq][kt*32 + 4hi + 8i + j] = key kr(i*4+j)
    u16x4 bg[4];
#pragma unroll
    for (int i = 0; i < 4; i++)
      bg[i] = *reinterpret_cast<const u16x4*>(Bb + kt * 32 + i * 8);
    // stage tile t+1 into the other buffer
    if (kt < 63) {
      char* dK = (char*)&Ks[cur ^ 1][0] + w * 4096;
      char* dV = (char*)&Vs[cur ^ 1][0] + w * 4096;
#pragma unroll
      for (int i = 0; i < 4; i++) {
        __builtin_amdgcn_global_load_lds(ksrc[i] + (size_t)(kt + 1) * 16384, dK + i * 1024, 16, 0, 0);
        __builtin_amdgcn_global_load_lds(vsrc[i] + (size_t)(kt + 1) * 64,    dV + i * 1024, 16, 0, 0);
      }
    }
    __builtin_amdgcn_sched_barrier(0);

    // ---- S^T = K @ Q^T on buf cur ----
    const char* KsC = (const char*)&Ks[cur][0];
    f32x16 s;
#pragma unroll
    for (int r = 0; r < 16; r++) s[r] = 0.f;
    const int kxor = lq << 4;
#pragma unroll
    for (int kc = 0; kc < 16; kc++) {
      bf16x8 kf = *reinterpret_cast<const bf16x8*>(KsC + lq * 512 + ((kc * 32 + hi * 16) ^ kxor));
      s = __builtin_amdgcn_mfma_f32_32x32x16_bf16(kf, qf[kc], s, 0, 0, 0);
    }
    // + bias (bg dead after this)
#pragma unroll
    for (int r = 0; r < 16; r++)
      s[r] += b2f((unsigned short)bg[r >> 2][r & 3]);

    // row max: 16 in-lane + xor32 (lanes lq, lq+32 share q-row)
    float pmax = s[0];
#pragma unroll
    for (int r = 1; r < 16; r++) pmax = fmaxf(pmax, s[r]);
    pmax = fmaxf(pmax, __shfl_xor(pmax, 32));

    // online-softmax rescale (always)
    const float mnew = fmaxf(mrun, pmax);
    const float scq = __expf(mrun - mnew);
    mrun = mnew;
    lrun *= scq;
    float sfac[16];
#pragma unroll
    for (int r = 0; r < 16; r++) sfac[r] = __shfl(scq, (r & 3) + 8 * (r >> 2) + 4 * hi);
#pragma unroll
    for (int dt = 0; dt < 8; dt++)
#pragma unroll
      for (int r = 0; r < 16; r++) O[dt][r] *= sfac[r];

    // exp + direct pack into PV A-fragments (V key columns pre-permuted to match)
    union { unsigned short u[8]; bf16x8 v; } pa0, pa1;
    float rs = 0.f;
#pragma unroll
    for (int j = 0; j < 8; j++) {
      const float p = __expf(s[j] - mrun);
      pa0.u[j] = bfbits(p);
      rs += b2f(pa0.u[j]);
    }
#pragma unroll
    for (int j = 0; j < 8; j++) {
      const float p = __expf(s[8 + j] - mrun);
      pa1.u[j] = bfbits(p);
      rs += b2f(pa1.u[j]);
    }
    rs += __shfl_xor(rs, 32);
    lrun += rs;

    // ---- PV: O[q][dim] += P @ V on buf cur ----
    const char* VsC = (const char*)&Vs[cur][0];
#pragma unroll
    for (int dt = 0; dt < 8; dt++) {
      const int row = dt * 32 + lq;
      const int gg = ((row >> 1) ^ (row >> 3)) & 3;
      bf16x8 v0 = *reinterpret_cast<const bf16x8*>(VsC + row * 64 + ((hi ^ gg) << 4));
      bf16x8 v1 = *reinterpret_cast<const bf16x8*>(VsC + row * 64 + (((2 + hi) ^ gg) << 4));
      O[dt] = __builtin_amdgcn_mfma_f32_32x32x16_bf16(pa0.v, v0, O[dt], 0, 0, 0);
      O[dt] = __builtin_amdgcn_mfma_f32_32x32x16_bf16(pa1.v, v1, O[dt], 0, 0, 0);
    }

    if (kt < 63) {
      asm volatile("s_waitcnt vmcnt(0)" ::: "memory");
      __builtin_amdgcn_sched_barrier(0);
      __builtin_amdgcn_s_barrier();
    }
  }

  // epilogue: O[dt] col = dim dt*32+lq, rows = q kr(r)
  const float rli = 1.0f / lrun;
  float rl[16];
#pragma unroll
  for (int r = 0; r < 16; r++) rl[r] = __shfl(rli, (r & 3) + 8 * (r >> 2) + 4 * hi);
#pragma unroll
  for (int dt = 0; dt < 8; dt++) {
    const int d = dt * 32 + lq;
#pragma unroll
    for (int r = 0; r < 16; r++) {
      const int row = q0 + (r & 3) + 8 * (r >> 2) + 4 * hi;
      const float v = O[dt][r] * rl[r];
      if (d < 64) {
        Hres[(size_t)(b * 2048 + row) * 512 + h * 64 + d] = __float2bfloat16(v);
      } else {
        const int c = (d - 64) >> 6, t = (d - 64) & 63;
        Vres[((size_t)(b * 2048 + row) * 3 + c) * 512 + h * 64 + t] = __float2bfloat16(v);
      }
    }
  }
}

// ---------------------------------------------------------------- launch
extern "C" void kernel_launch(void* const* d_in, const int* in_sizes, int n_in,
                              void* d_out, int out_size, void* d_ws, size_t ws_size,
                              hipStream_t stream) {
  const float* H   = (const float*)d_in[0];
  const float* V   = (const float*)d_in[1];
  const float* Dm  = (const float*)d_in[2];
  const float* rbf = (const float*)d_in[3];
  const int*   mask= (const int*)d_in[4];
  const float* Wq  = (const float*)d_in[5];
  const float* bq  = (const float*)d_in[6];
  const float* Wk  = (const float*)d_in[7];
  const float* bk  = (const float*)d_in[8];
  const float* Wv  = (const float*)d_in[9];
  const float* bv  = (const float*)d_in[10];
  const float* Wvv = (const float*)d_in[11];
  const float* Wo  = (const float*)d_in[12];
  const float* bo  = (const float*)d_in[13];
  const float* Wvo = (const float*)d_in[14];

  char* ws = (char*)d_ws;
  bf16* Hbf  = (bf16*)(ws);                    // Hbf||Vbf contiguous [32768,512]
  bf16* Wall = (bf16*)(ws + 33554432);
  bf16* Qw   = (bf16*)(ws + 39845888);         // Qw||Kw contiguous
  bf16* Kw   = Qw + 16777216;
  bf16* Vtw  = (bf16*)(ws + 106954752);
  bf16* Hres = Hbf;                             // aliases (attn output overwrites inputs' bf16)
  bf16* Wqb  = Wall;
  bf16* Wvb  = Wall + 2097152;
  bf16* Wvvb = Wall + 2359296;
  bf16* Wob  = Wall + 2621440;
  bf16* Wvob = Wall + 2883584;
  bf16* Bcb  = (bf16*)d_out;                   // 33.5MB bf16 in d_out; read fully by attn
                                               // before the final GEMM overwrites d_out

  bias_combine<<<16384, 256, 0, stream>>>(Dm, rbf, mask, Bcb);
  cvt_plain<<<4096, 256, 0, stream>>>(H, Hbf, 4194304);
  cvt_vperm<<<12288, 256, 0, stream>>>(V, Hbf + 4194304);
  cvt_weights<<<3072, 256, 0, stream>>>(Wq, Wk, Wv, Wvv, Wo, Wvo, Wall);

  // Q||K projection: A=Hbf, W=Wq||Wk (contiguous in Wall), out=Qw||Kw
  gemm2<0><<<dim3(32, 64), 256, 0, stream>>>(Hbf, Wqb, nullptr, bq, bk, Qw);
  // Hv||Vv -> Vt: A=Hbf||Vbf, W selected per block-row
  gemm2<1><<<dim3(4, 256), 256, 0, stream>>>(Hbf, Wvb, Wvvb, bv, nullptr, Vtw);

  attn_kernel<<<512, 256, 0, stream>>>(Qw, Kw, Vtw, Bcb, Hres, Hbf + 4194304);

  // output projection: A=Hres||Vres, W selected per block-row, out=d_out (f32)
  gemm2<2><<<dim3(4, 256), 256, 0, stream>>>(Hbf, Wob, Wvob, bo, nullptr, d_out);
}